// Round 3
// baseline (142.514 us; speedup 1.0000x reference)
//
#include <hip/hip_runtime.h>
#include <stdint.h>

// image (1,1024,1024) f32, x (16,1,1024,1024) f32, W_KL (9,1,3,3) f32, b_KL (9,) f32.
// y[b,h,w] = sum_{a,d} (conv(image,W_KL)[a*3+d][h,w] + b[a*3+d]) * x[b,h+a-1,w+d-1]
#define IH 1024
#define IW 1024
#define NB 16
#define BPB 4   // batches per block (gridDim.y = NB/BPB)

typedef float v4f __attribute__((ext_vector_type(4)));

// Direct global->LDS copy, 16B per lane, no VGPR destination: the register
// allocator CANNOT serialize these (rounds 1-2 failure mode). LDS dest is
// wave-uniform; HW writes lane l's 16B at ldsbase + l*16, matching the
// per-lane global addresses g + l*16 (linear, guide m97/m104 contract).
__device__ __forceinline__ void glds16(const float* g, float* l) {
    __builtin_amdgcn_global_load_lds(
        (const __attribute__((address_space(1))) void*)g,
        (__attribute__((address_space(3))) void*)l, 16, 0, 0);
}

// Image window in registers (round-2 verified path): aligned v4f core +
// scalar halo dwords, rows clamped in-bounds; padding handled by masks below.
struct RawWin { v4f mv[3]; float fl[3]; float fr[3]; };

__device__ __forceinline__ void issue_win(const float* __restrict__ plane,
                                          int h, int w0, RawWin& rw) {
#pragma unroll
    for (int a = 0; a < 3; ++a) {
        const int hh = h + a - 1;
        const int hc = (hh < 0) ? 0 : (hh >= IH ? IH - 1 : hh);
        const float* rowp = plane + (size_t)hc * IW;
        rw.fl[a] = rowp[w0 > 0 ? w0 - 1 : 0];
        rw.mv[a] = *(const v4f*)(rowp + w0);
        rw.fr[a] = rowp[w0 + 4 < IW ? w0 + 4 : IW - 1];
    }
}

__device__ __forceinline__ void fin_win_img(const RawWin& rw, int h, int w0,
                                            float win[3][6]) {
#pragma unroll
    for (int a = 0; a < 3; ++a) {
        const int hh = h + a - 1;
        const bool rowok = (hh >= 0) & (hh < IH);
        win[a][0] = (rowok && w0 > 0)      ? rw.fl[a]   : 0.f;
        win[a][1] = rowok ? rw.mv[a].x : 0.f;
        win[a][2] = rowok ? rw.mv[a].y : 0.f;
        win[a][3] = rowok ? rw.mv[a].z : 0.f;
        win[a][4] = rowok ? rw.mv[a].w : 0.f;
        win[a][5] = (rowok && w0 + 4 < IW) ? rw.fr[a]   : 0.f;
    }
}

// Block = ONE output row (256 thr x 4 px = 1024 px), BPB batches.
// Stage 3 x-rows per batch into LDS via global_load_lds (48 KiB, all 12
// issues per wave up front -> guaranteed in-flight regardless of regalloc),
// compute Kv from registers while they fly, one barrier, then consume all
// BPB batches from LDS with conflict-free ds_read_b128 sweeps.
__global__ __launch_bounds__(256) void fused_lds(
    const float* __restrict__ image,
    const float* __restrict__ x,
    const float* __restrict__ Wk,
    const float* __restrict__ bk,
    float* __restrict__ out)
{
    __shared__ float lds[BPB][3][IW];     // 48 KiB -> 3 blocks/CU

    const int tid  = threadIdx.x;         // 0..255
    const int lane = tid & 63;
    const int wv   = tid >> 6;            // wave 0..3 stages quarter wv
    const int h    = blockIdx.x;          // output row
    const int b0   = blockIdx.y * BPB;
    const int w0   = tid * 4;             // 4 px per thread, full row covered

    const size_t plane = (size_t)IH * IW;
    const float* __restrict__ xb = x + (size_t)b0 * plane;

    // 1) image window loads FIRST (so Kv's wait is vmcnt(12), keeping the
    //    12 stage ops below in flight during the Kv FMAs).
    RawWin rimg;
    issue_win(image, h, w0, rimg);

    // 2) stage BPB x-windows: wave wv copies bytes [wv*1K, wv*1K+1K) of each
    //    of the 3 rows of each batch. Rows clamped; pad rows masked via Kv.
    const int qoff = wv * 256 + lane * 4; // float offset of this lane's 16B
#pragma unroll
    for (int b = 0; b < BPB; ++b)
#pragma unroll
        for (int a = 0; a < 3; ++a) {
            const int hh = h + a - 1;
            const int hc = (hh < 0) ? 0 : (hh >= IH ? IH - 1 : hh);
            glds16(xb + (size_t)b * plane + (size_t)hc * IW + qoff,
                   &lds[b][a][wv * 256]);
        }
    __builtin_amdgcn_sched_barrier(0);    // keep stage issues above compute

    // 3) conv weights / bias (uniform -> SGPR) + per-pixel kernels Kv
    float wk[81];
#pragma unroll
    for (int i = 0; i < 81; ++i) wk[i] = Wk[i];
    float bb[9];
#pragma unroll
    for (int c = 0; c < 9; ++c) bb[c] = bk[c];

    float p[3][6];
    fin_win_img(rimg, h, w0, p);
    float Kv[4][9];
#pragma unroll
    for (int j = 0; j < 4; ++j)
#pragma unroll
        for (int c = 0; c < 9; ++c) {
            float acc = bb[c];
#pragma unroll
            for (int a = 0; a < 3; ++a)
#pragma unroll
                for (int d = 0; d < 3; ++d)
                    acc = fmaf(wk[c * 9 + a * 3 + d], p[a][j + d], acc);
            Kv[j][c] = acc;
        }

    // Row-pad masking for the APPLY step folded into Kv (uniform per block):
    // x_pad row h-1 (h==0) / h+1 (h==IH-1) is zero -> zero those 3 taps.
    {
        const bool top = (h == 0);
        const bool bot = (h == IH - 1);
#pragma unroll
        for (int j = 0; j < 4; ++j)
#pragma unroll
            for (int d = 0; d < 3; ++d) {
                Kv[j][d]     = top ? 0.f : Kv[j][d];
                Kv[j][6 + d] = bot ? 0.f : Kv[j][6 + d];
            }
    }

    // 4) all stages visible block-wide
    asm volatile("s_waitcnt vmcnt(0)" ::: "memory");
    __syncthreads();

    // 5) consume BPB batches from LDS. Per row: 3 aligned ds_read_b128
    //    (sequential bank sweeps, conflict-free); w-halos are true image
    //    edges only (full row staged) -> value-select zeros.
    float* __restrict__ ob = out + (size_t)b0 * plane + (size_t)h * IW + w0;
    const int wl = (w0 >= 4) ? w0 - 4 : 0;          // aligned left-halo read
    const int wr = (w0 + 4 < IW) ? w0 + 4 : IW - 4; // aligned right-halo read
#pragma unroll
    for (int b = 0; b < BPB; ++b) {
        float win[3][6];
#pragma unroll
        for (int a = 0; a < 3; ++a) {
            const v4f lv = *(const v4f*)&lds[b][a][wl];
            const v4f mv = *(const v4f*)&lds[b][a][w0];
            const v4f rv = *(const v4f*)&lds[b][a][wr];
            win[a][0] = (w0 > 0)      ? lv.w : 0.f;
            win[a][1] = mv.x;
            win[a][2] = mv.y;
            win[a][3] = mv.z;
            win[a][4] = mv.w;
            win[a][5] = (w0 + 4 < IW) ? rv.x : 0.f;
        }
        v4f y;
#pragma unroll
        for (int j = 0; j < 4; ++j) {
            float acc = 0.f;
#pragma unroll
            for (int a = 0; a < 3; ++a)
#pragma unroll
                for (int d = 0; d < 3; ++d)
                    acc = fmaf(Kv[j][a * 3 + d], win[a][j + d], acc);
            y[j] = acc;
        }
        __builtin_nontemporal_store(y, (v4f*)(ob + (size_t)b * plane));
    }
}

extern "C" void kernel_launch(void* const* d_in, const int* in_sizes, int n_in,
                              void* d_out, int out_size, void* d_ws, size_t ws_size,
                              hipStream_t stream) {
    const float* image = (const float*)d_in[0]; // 1*1024*1024
    const float* x     = (const float*)d_in[1]; // 16*1*1024*1024
    const float* Wk    = (const float*)d_in[2]; // 9*1*3*3
    const float* bk    = (const float*)d_in[3]; // 9
    float* out = (float*)d_out;                 // 16*1024*1024 f32

    dim3 block(256);
    dim3 grid(IH, NB / BPB);                    // (1024, 4) = 4096 blocks
    fused_lds<<<grid, block, 0, stream>>>(image, x, Wk, bk, out);
}

// Round 4
// 123.898 us; speedup vs baseline: 1.1502x; 1.1502x over previous
//
#include <hip/hip_runtime.h>

// image (1,1024,1024) f32, x (16,1,1024,1024) f32, W_KL (9,1,3,3) f32, b_KL (9,) f32.
// y[b,h,w] = sum_{a,d} (conv(image,W_KL)[a*3+d][h,w] + b[a*3+d]) * x[b,h+a-1,w+d-1]
#define IH 1024
#define IW 1024
#define NB 16

typedef float v4f __attribute__((ext_vector_type(4)));

__device__ __forceinline__ void glds16(const float* g, float* l) {
    __builtin_amdgcn_global_load_lds(
        (const __attribute__((address_space(1))) void*)g,
        (__attribute__((address_space(3))) void*)l, 16, 0, 0);
}

// Image window in registers: aligned v4f core + scalar halo dwords, rows
// clamped in-bounds; zero-padding applied in fin_win_img.
struct RawWin { v4f mv[3]; float fl[3]; float fr[3]; };

__device__ __forceinline__ void issue_win(const float* __restrict__ plane,
                                          int h, int w0, RawWin& rw) {
#pragma unroll
    for (int a = 0; a < 3; ++a) {
        const int hh = h + a - 1;
        const int hc = (hh < 0) ? 0 : (hh >= IH ? IH - 1 : hh);
        const float* rowp = plane + (size_t)hc * IW;
        rw.fl[a] = rowp[w0 > 0 ? w0 - 1 : 0];
        rw.mv[a] = *(const v4f*)(rowp + w0);
        rw.fr[a] = rowp[w0 + 4 < IW ? w0 + 4 : IW - 1];
    }
}

__device__ __forceinline__ void fin_win_img(const RawWin& rw, int h, int w0,
                                            float win[3][6]) {
#pragma unroll
    for (int a = 0; a < 3; ++a) {
        const int hh = h + a - 1;
        const bool rowok = (hh >= 0) & (hh < IH);
        win[a][0] = (rowok && w0 > 0)      ? rw.fl[a]   : 0.f;
        win[a][1] = rowok ? rw.mv[a].x : 0.f;
        win[a][2] = rowok ? rw.mv[a].y : 0.f;
        win[a][3] = rowok ? rw.mv[a].z : 0.f;
        win[a][4] = rowok ? rw.mv[a].w : 0.f;
        win[a][5] = (rowok && w0 + 4 < IW) ? rw.fr[a]   : 0.f;
    }
}

// Block = 4 rows x 256 cols (wave wv owns row h0+wv, lanes cover 256 cols,
// 4 px/lane). All 16 batches per block. Per batch, the 6-row x-tile
// (rows h0-1..h0+4, block's 256-col slice) is staged into LDS via
// global_load_lds, double-buffered. Sync per batch = ONE raw s_barrier
// preceded by a COUNTED s_waitcnt vmcnt(6) (queue at wait, oldest first:
// [store(b-1), stage(b+1) x G, halo(b+1) x 6] -> retire store+stage, keep
// halos in flight). __syncthreads would drain vmcnt(0) and serialize the
// prefetch (the m97 ~20% barrier-drain stall).
__global__ __launch_bounds__(256, 4) void fused_dbuf(
    const float* __restrict__ image,
    const float* __restrict__ x,
    const float* __restrict__ Wk,
    const float* __restrict__ bk,
    float* __restrict__ out)
{
    __shared__ float lds[2][6][256];          // 12 KiB -> 4 blocks/CU fits

    const int tx = threadIdx.x;               // lane 0..63
    const int wv = threadIdx.y;               // wave 0..3 = row within group

    // XCD-clustered swizzle: xcd = hwid%8 owns a contiguous band of 32
    // row-groups (128 rows), so the shared staging rows between vertically
    // adjacent groups hit the SAME XCD's L2 (round-3: they missed, 2x fetch).
    const int hwid  = blockIdx.x;             // 0..1023
    const int xcd   = hwid & 7;
    const int chunk = hwid >> 3;              // 0..127
    const int bx    = chunk & 3;              // col-tile 0..3
    const int g     = xcd * 32 + (chunk >> 2);// row-group 0..255 (bijective)
    const int c0    = bx * 256;
    const int h0    = g * 4;
    const int h     = h0 + wv;
    const int lc    = tx * 4;                 // local col of first out px
    const int w0    = c0 + lc;                // global col

    const size_t plane = (size_t)IH * IW;

    // Opaque zero in a VGPR: added to halo-load addresses so the (wave-
    // uniform) broadcast loads cannot be scalarized to SMEM — they must stay
    // VMEM or the vmcnt(6) bookkeeping below would be wrong.
    int zv; asm("v_mov_b32 %0, 0" : "=v"(zv));

    // stage batch b's 6-row tile into lds[buf]: wave wv does row wv
    // (+ row wv+4 for wv<2): G = 2,2,1,1 glds per wave (count-independent
    // vmcnt math below).
    auto stage = [&](int b, int buf) {
        const float* xb = x + (size_t)b * plane;
        int gr = h0 - 1 + wv; gr = gr < 0 ? 0 : gr;               // rows -1..2 clamp lo
        glds16(xb + (size_t)gr * IW + c0 + tx * 4, &lds[buf][wv][0]);
        if (wv < 2) {
            int g2 = h0 + 3 + wv; g2 = g2 > IH - 1 ? IH - 1 : g2; // rows 3..4 clamp hi
            glds16(xb + (size_t)g2 * IW + c0 + tx * 4, &lds[buf][wv + 4][0]);
        }
    };
    // column-halo for batch b: cols c0-1 / c0+256 for this thread's 3 rows,
    // broadcast loads (all lanes same address), 6 VMEM ops per wave.
    auto halo = [&](int b, float* HL, float* HR) {
        const float* xb = x + (size_t)b * plane;
        const int cl = (c0 > 0) ? c0 - 1 : 0;
        const int cr = (c0 + 256 < IW) ? c0 + 256 : IW - 1;
#pragma unroll
        for (int a = 0; a < 3; ++a) {
            int gr = h + a - 1; gr = gr < 0 ? 0 : (gr > IH - 1 ? IH - 1 : gr);
            const float* rp = xb + (size_t)gr * IW;
            HL[a] = rp[cl + zv];
            HR[a] = rp[cr + zv];
        }
    };

    // ---- issue order: image (oldest), stage(0), halo(0) ----
    // Kv's auto-wait retires only the image loads (in-order retirement),
    // so stage(0) keeps flying under the 324 Kv FMAs.
    RawWin rimg;
    issue_win(image, h, w0, rimg);
    stage(0, 0);
    float hl[2][3], hr[2][3];
    halo(0, hl[0], hr[0]);

    // conv weights / bias: uniform addresses -> scalar loads (lgkmcnt, does
    // not perturb the vmcnt counting).
    float wkk[81];
#pragma unroll
    for (int i = 0; i < 81; ++i) wkk[i] = Wk[i];
    float bb[9];
#pragma unroll
    for (int c = 0; c < 9; ++c) bb[c] = bk[c];

    // ---- K phase ----
    float p[3][6];
    fin_win_img(rimg, h, w0, p);
    float Kv[4][9];
#pragma unroll
    for (int j = 0; j < 4; ++j)
#pragma unroll
        for (int c = 0; c < 9; ++c) {
            float acc = bb[c];
#pragma unroll
            for (int a = 0; a < 3; ++a)
#pragma unroll
                for (int d = 0; d < 3; ++d)
                    acc = fmaf(wkk[c * 9 + a * 3 + d], p[a][j + d], acc);
            Kv[j][c] = acc;
        }
    // Row-pad masking folded into Kv: x_pad rows above h=0 / below h=1023
    // are zero -> zero those taps; staged clamp-row garbage then contributes 0.
    {
        const bool top = (h == 0);
        const bool bot = (h == IH - 1);
#pragma unroll
        for (int j = 0; j < 4; ++j)
#pragma unroll
            for (int d = 0; d < 3; ++d) {
                Kv[j][d]     = top ? 0.f : Kv[j][d];
                Kv[j][6 + d] = bot ? 0.f : Kv[j][6 + d];
            }
    }

    // prologue sync: queue here = [stage(0) x G, halo(0) x 6] (image already
    // retired by Kv's waits) -> vmcnt(6) retires exactly stage(0).
    asm volatile("s_waitcnt vmcnt(6)" ::: "memory");
    __builtin_amdgcn_sched_barrier(0);
    __builtin_amdgcn_s_barrier();
    __builtin_amdgcn_sched_barrier(0);

    v4f yv[2];
    float* obp = out + (size_t)h * IW + w0;

#pragma unroll
    for (int b = 0; b < NB; ++b) {
        // store of previous batch AFTER the barrier (keeps it oldest in the
        // vm queue -> vmcnt(6) retires it together with stage(b+1)).
        if (b > 0)
            __builtin_nontemporal_store(yv[(b - 1) & 1],
                                        (v4f*)(obp + (size_t)(b - 1) * plane));
        if (b + 1 < NB) {
            stage(b + 1, (b + 1) & 1);
            halo(b + 1, hl[(b + 1) & 1], hr[(b + 1) & 1]);
        }
        // ---- consume batch b from lds[b&1] ----
        {
            const int ll = (tx > 0)  ? lc - 4 : 0;    // aligned left b128
            const int lr = (tx < 63) ? lc + 4 : 252;  // aligned right b128
            const float* lb = &lds[b & 1][0][0];
            float win[3][6];
#pragma unroll
            for (int a = 0; a < 3; ++a) {
                const float* rowp = lb + (wv + a) * 256;
                const v4f lv = *(const v4f*)(rowp + ll);
                const v4f mv = *(const v4f*)(rowp + lc);
                const v4f rv = *(const v4f*)(rowp + lr);
                const float le = (tx == 0)  ? hl[b & 1][a] : lv.w;
                const float re = (tx == 63) ? hr[b & 1][a] : rv.x;
                win[a][0] = (w0 > 0)      ? le : 0.f;
                win[a][1] = mv.x; win[a][2] = mv.y;
                win[a][3] = mv.z; win[a][4] = mv.w;
                win[a][5] = (w0 + 4 < IW) ? re : 0.f;
            }
            v4f yy;
#pragma unroll
            for (int j = 0; j < 4; ++j) {
                float acc = 0.f;
#pragma unroll
                for (int a = 0; a < 3; ++a)
#pragma unroll
                    for (int d = 0; d < 3; ++d)
                        acc = fmaf(Kv[j][a * 3 + d], win[a][j + d], acc);
                yy[j] = acc;
            }
            yv[b & 1] = yy;
        }
        if (b + 1 < NB) {
            // counted drain: retire [store(b-1), stage(b+1) x G], keep
            // halo(b+1) x 6 in flight. Then raw barrier (no vmcnt(0) drain).
            asm volatile("s_waitcnt vmcnt(6)" ::: "memory");
            __builtin_amdgcn_sched_barrier(0);
            __builtin_amdgcn_s_barrier();
            __builtin_amdgcn_sched_barrier(0);
        }
    }
    __builtin_nontemporal_store(yv[(NB - 1) & 1],
                                (v4f*)(obp + (size_t)(NB - 1) * plane));
}

extern "C" void kernel_launch(void* const* d_in, const int* in_sizes, int n_in,
                              void* d_out, int out_size, void* d_ws, size_t ws_size,
                              hipStream_t stream) {
    const float* image = (const float*)d_in[0]; // 1*1024*1024
    const float* x     = (const float*)d_in[1]; // 16*1*1024*1024
    const float* Wk    = (const float*)d_in[2]; // 9*1*3*3
    const float* bk    = (const float*)d_in[3]; // 9
    float* out = (float*)d_out;                 // 16*1024*1024 f32

    dim3 block(64, 4);
    dim3 grid(1024);                            // 4 blocks/CU, uniform work
    fused_dbuf<<<grid, block, 0, stream>>>(image, x, Wk, bk, out);
}